// Round 3
// baseline (1613.246 us; speedup 1.0000x reference)
//
#include <hip/hip_runtime.h>

// FrameOTAMDistanceNetwork: per (s,b): 8x8 cosine matrix between 8 support
// frames and 8 target frames (each 2048 fp32), then OTAM soft-DP both ways.
// Memory-bound: 436 MB compulsory reads -> ~70us floor at 6.3 TB/s.
//
// V3b: one block per (b, half-of-s); tv[b] staged ONCE, v-norms ONCE.
// Single-s register u-buffer (64 VGPR) with prefetch-in-place into dead
// regs -> peak live ~100 VGPR, NO SPILLS (V2's 2.2 GB scratch WRITE_SIZE
// came from a 190-reg peak vs the compiler's 128-reg choice).
// One barrier per s (slot-parity sdot); DP tail rotates across waves.
// bid remap co-locates both halves of b on one XCD (tv L2-resident, 2MB/XCD);
// sv loads are non-temporal (native ext_vector type — HIP float4 is a class
// and __builtin_nontemporal_load rejects it) so the stream doesn't evict tv.

typedef float vf4 __attribute__((ext_vector_type(4)));

constexpr int kNF   = 8;
constexpr int kFLEN = 2048;   // DF / NFRAMES
constexpr int kSeq  = 25;
constexpr int kBS   = 256;
constexpr int kDF   = 16384;
constexpr float kLam    = 0.1f;
constexpr float kInvLam = 10.0f;

__global__ __launch_bounds__(256, 2) void otam_kernel(
    const float* __restrict__ sv,   // [Seq, BS, DF]
    const float* __restrict__ tv,   // [BS, DF]
    float* __restrict__ out)        // [Seq, BS]
{
    __shared__ float V[kDF];               // 64 KB: target frames for this b
    __shared__ float sdot[2][kNF][kNF];    // [s parity][i][j] raw dots
    __shared__ float rsnu[2][kNF];         // rsqrt(|u_i|^2) per parity
    __shared__ float rnv[kNF];             // rsqrt(|v_j|^2), once per block

    // ---- bid -> (b, half) such that both halves of b share an XCD ----
    // XCD = bid % 8 (round-robin dispatch). bids p and p+8 share an XCD.
    const int bid  = blockIdx.x;
    const int xcd  = bid & 7;
    const int j8   = bid >> 3;            // 0..63
    const int b    = ((j8 >> 1) << 3) | xcd;
    const int half = j8 & 1;

    const int t    = threadIdx.x;
    const int g    = t >> 5;              // group 0..7: owns support frame g
    const int l    = t & 31;              // lane within group
    const int lane = t & 63;
    const int w    = t >> 6;              // wave id 0..3

    const int sbeg = half ? 12 : 0;
    const int scnt = half ? 13 : 12;

    // ---- stage tv[b] into LDS (4096 float4, coalesced; temps die at ds_write) ----
    {
        const float4* tv4 = (const float4*)(tv + (size_t)b * kDF);
        float4* V4 = (float4*)V;
        #pragma unroll
        for (int it = 0; it < 16; ++it)
            V4[it * 256 + t] = tv4[it * 256 + t];
    }

    // ---- prefetch first s into u regs (64 VGPR, single buffer) ----
    vf4 u[16];
    {
        const vf4* p = (const vf4*)(sv + ((size_t)sbeg * kBS + b) * kDF + (size_t)g * kFLEN);
        #pragma unroll
        for (int c = 0; c < 16; ++c) u[c] = __builtin_nontemporal_load(&p[c * 32 + l]);
    }
    __syncthreads();

    // ---- v norms: once per block (group g owns |v_g|^2) ----
    {
        float v2 = 0.f;
        const float4* Vg = (const float4*)(V + g * kFLEN);
        #pragma unroll
        for (int c = 0; c < 16; ++c) {
            float4 v = Vg[c * 32 + l];
            v2 = fmaf(v.x, v.x, fmaf(v.y, v.y, fmaf(v.z, v.z, fmaf(v.w, v.w, v2))));
        }
        #pragma unroll
        for (int m = 16; m >= 1; m >>= 1) v2 += __shfl_xor(v2, m, 64);
        if (l == 0) rnv[g] = rsqrtf(v2);
        // first read of rnv is after s0's barrier -> ordered
    }

    for (int k = 0; k < scnt; ++k) {
        const int slot = k & 1;

        // ---- dots: group g's support frame vs all 8 target frames ----
        float dot[kNF] = {};
        float n0 = 0.f;
        #pragma unroll
        for (int c = 0; c < 16; ++c) {
            vf4 a = u[c];
            n0 = fmaf(a.x, a.x, fmaf(a.y, a.y, fmaf(a.z, a.z, fmaf(a.w, a.w, n0))));
            #pragma unroll
            for (int j = 0; j < kNF; ++j) {
                // two wave-halves read identical V addresses -> broadcast, free
                float4 v = ((const float4*)(V + j * kFLEN))[c * 32 + l];
                dot[j] = fmaf(a.x, v.x, fmaf(a.y, v.y, fmaf(a.z, v.z, fmaf(a.w, v.w, dot[j]))));
            }
        }

        // ---- u regs are dead: prefetch next s in place; latency hides
        //      under reduce + DP + barrier (no extra registers) ----
        if (k + 1 < scnt) {
            const vf4* p = (const vf4*)(sv + ((size_t)(sbeg + k + 1) * kBS + b) * kDF + (size_t)g * kFLEN);
            #pragma unroll
            for (int c = 0; c < 16; ++c) u[c] = __builtin_nontemporal_load(&p[c * 32 + l]);
        }

        // ---- reduce 9 values across the 32-lane group (xor <=16 stays in-group) ----
        #pragma unroll
        for (int m = 16; m >= 1; m >>= 1) {
            n0 += __shfl_xor(n0, m, 64);
            #pragma unroll
            for (int j = 0; j < kNF; ++j) dot[j] += __shfl_xor(dot[j], m, 64);
        }
        if (l == 0) {
            rsnu[slot][g] = rsqrtf(n0);
            #pragma unroll
            for (int j = 0; j < kNF; ++j) sdot[slot][g][j] = dot[j];
        }
        __syncthreads();   // the ONLY barrier per s (slot parity covers reuse)

        // ---- two DPs on lanes 0..15 of wave (k&3): 0-7 dp(D), 8-15 dp(D^T).
        //      Normalization fused into the matrix access. ----
        if (w == (k & 3) && lane < 16) {
            const int  r  = lane & 7;
            const bool xp = lane >= 8;
            const float (*M)[kNF] = sdot[slot];
            const float* ru = rsnu[slot];

            auto Dm = [&](int rr, int ii) -> float {
                return xp ? M[ii][rr] * ru[ii] * rnv[rr]
                          : M[rr][ii] * ru[rr] * rnv[ii];
            };

            float prev = Dm(r, 0);
            #pragma unroll
            for (int i = 1; i < kNF; ++i) {
                float up = __shfl_up(prev, 1, 64);  // prev[r-1]; unused when r==0
                float d  = Dm(r, i);
                float mx = fmaxf(up, prev);
                float mn = fminf(up, prev);
                float lse = mx + kLam * log1pf(expf((mn - mx) * kInvLam));
                prev = (r == 0) ? (prev + d) : (lse + d);
            }
            // lam*logsumexp over the 8 rows (xor 4,2,1 stays in 8-lane group)
            float mx = prev;
            #pragma unroll
            for (int m = 4; m >= 1; m >>= 1) mx = fmaxf(mx, __shfl_xor(mx, m, 64));
            float e = expf((prev - mx) * kInvLam);
            #pragma unroll
            for (int m = 4; m >= 1; m >>= 1) e += __shfl_xor(e, m, 64);
            float res = mx + kLam * logf(e);

            float resT = __shfl(res, r + 8, 64);    // pair dp1 lane with dp2 lane
            if (lane == 0) out[(size_t)(sbeg + k) * kBS + b] = 0.5f * (res + resT);
        }
    }
}

extern "C" void kernel_launch(void* const* d_in, const int* in_sizes, int n_in,
                              void* d_out, int out_size, void* d_ws, size_t ws_size,
                              hipStream_t stream) {
    const float* sv = (const float*)d_in[0];
    const float* tv = (const float*)d_in[1];
    float* out = (float*)d_out;
    otam_kernel<<<dim3(2 * kBS), dim3(256), 0, stream>>>(sv, tv, out);
}

// Round 4
// 566.365 us; speedup vs baseline: 2.8484x; 2.8484x over previous
//
#include <hip/hip_runtime.h>

// FrameOTAMDistanceNetwork: per (s,b): 8x8 cosine matrix between 8 support
// frames and 8 target frames (each 2048 fp32), then OTAM soft-DP both ways.
// Memory-bound: 436 MB compulsory reads -> ~70us floor at 6.3 TB/s.
//
// V4: back to V1's per-(s,b)-block structure (V2/V3's persistent-loop
// register arrays spilled: 2.5 GB scratch WRITE_SIZE, 8x kernel regression).
// Improvements over V1:
//  - 64-lane groups own TWO u-frames: each LDS V read feeds 2 dot chains
//    (V1's two half-waves read identical addresses) -> LDS traffic halved.
//  - XCD-aware bid remap: all 25 s-blocks of one b on one XCD -> tv HBM
//    traffic 134 MB -> ~17 MB; sv reads form contiguous 2 MB slabs per XCD.
//  - normalization fused into DP lanes (one fewer barrier, validated V3b).
//  - sv loads non-temporal (streamed once; don't evict tv from L2).

typedef float vf4 __attribute__((ext_vector_type(4)));

constexpr int kNF   = 8;
constexpr int kFLEN = 2048;   // DF / NFRAMES
constexpr int kSeq  = 25;
constexpr int kBS   = 256;
constexpr int kDF   = 16384;
constexpr float kLam    = 0.1f;
constexpr float kInvLam = 10.0f;

__global__ __launch_bounds__(256, 2) void otam_kernel(
    const float* __restrict__ sv,   // [Seq, BS, DF]
    const float* __restrict__ tv,   // [BS, DF]
    float* __restrict__ out)        // [Seq, BS]
{
    __shared__ float V[kDF];            // 64 KB: target frames for this b
    __shared__ float sdot[kNF][kNF];    // raw dot(u_i, v_j)
    __shared__ float rsnu[kNF];         // rsqrt(|u_i|^2)
    __shared__ float rnv[kNF];          // rsqrt(|v_j|^2)

    // ---- XCD-aware remap: XCD = bid%8 (round-robin dispatch). Give each
    //      XCD 32 consecutive b's x 25 s's -> tv[b] read by ONE XCD only. ----
    const int bid = blockIdx.x;         // 6400 = 8 XCDs * 32 b * 25 s
    const int xcd = bid & 7;
    const int idx = bid >> 3;           // 0..799
    const int q   = idx / 25;           // 0..31  (b within XCD)
    const int s   = idx - q * 25;       // 0..24
    const int b   = (xcd << 5) | q;

    const int t    = threadIdx.x;
    const int w    = t >> 6;            // wave 0..3: owns u-frames 2w, 2w+1
    const int lane = t & 63;

    // ---- issue u-frame loads first (HBM, longest latency); 64 VGPR total,
    //      dead after the dot loop -> no pressure across barriers ----
    vf4 ua[8], ub[8];
    {
        const float* row = sv + ((size_t)s * kBS + b) * kDF;
        const vf4* pa = (const vf4*)(row + (2 * w) * kFLEN);
        const vf4* pb = (const vf4*)(row + (2 * w + 1) * kFLEN);
        #pragma unroll
        for (int c = 0; c < 8; ++c) {
            ua[c] = __builtin_nontemporal_load(&pa[c * 64 + lane]);
            ub[c] = __builtin_nontemporal_load(&pb[c * 64 + lane]);
        }
    }

    // ---- stage tv[b] into LDS (4096 float4, coalesced; L2-resident) ----
    {
        const vf4* tv4 = (const vf4*)(tv + (size_t)b * kDF);
        vf4* V4 = (vf4*)V;
        #pragma unroll
        for (int it = 0; it < 16; ++it)
            V4[it * 256 + t] = tv4[it * 256 + t];
    }
    __syncthreads();

    // ---- v norms: wave w computes |v_2w|^2 and |v_2w+1|^2 from LDS ----
    {
        float na = 0.f, nb = 0.f;
        const vf4* Va = (const vf4*)(V + (2 * w) * kFLEN);
        const vf4* Vb = (const vf4*)(V + (2 * w + 1) * kFLEN);
        #pragma unroll
        for (int c = 0; c < 8; ++c) {
            vf4 a = Va[c * 64 + lane], e = Vb[c * 64 + lane];
            na = fmaf(a.x, a.x, fmaf(a.y, a.y, fmaf(a.z, a.z, fmaf(a.w, a.w, na))));
            nb = fmaf(e.x, e.x, fmaf(e.y, e.y, fmaf(e.z, e.z, fmaf(e.w, e.w, nb))));
        }
        #pragma unroll
        for (int m = 32; m >= 1; m >>= 1) {
            na += __shfl_xor(na, m, 64);
            nb += __shfl_xor(nb, m, 64);
        }
        if (lane == 0) { rnv[2 * w] = rsqrtf(na); rnv[2 * w + 1] = rsqrtf(nb); }
        // first read of rnv is after the pre-DP barrier -> ordered
    }

    // ---- dots: each V element read ONCE per wave, feeds BOTH u-frames ----
    float da[kNF] = {}, db[kNF] = {};
    float na = 0.f, nb = 0.f;
    #pragma unroll
    for (int c = 0; c < 8; ++c) {
        vf4 a = ua[c], e = ub[c];
        na = fmaf(a.x, a.x, fmaf(a.y, a.y, fmaf(a.z, a.z, fmaf(a.w, a.w, na))));
        nb = fmaf(e.x, e.x, fmaf(e.y, e.y, fmaf(e.z, e.z, fmaf(e.w, e.w, nb))));
        #pragma unroll
        for (int j = 0; j < kNF; ++j) {
            vf4 v = ((const vf4*)(V + j * kFLEN))[c * 64 + lane];  // 1KB contiguous, conflict-free
            da[j] = fmaf(a.x, v.x, fmaf(a.y, v.y, fmaf(a.z, v.z, fmaf(a.w, v.w, da[j]))));
            db[j] = fmaf(e.x, v.x, fmaf(e.y, v.y, fmaf(e.z, v.z, fmaf(e.w, v.w, db[j]))));
        }
    }

    // ---- reduce 18 values across the 64-lane wave ----
    #pragma unroll
    for (int m = 32; m >= 1; m >>= 1) {
        na += __shfl_xor(na, m, 64);
        nb += __shfl_xor(nb, m, 64);
        #pragma unroll
        for (int j = 0; j < kNF; ++j) {
            da[j] += __shfl_xor(da[j], m, 64);
            db[j] += __shfl_xor(db[j], m, 64);
        }
    }
    if (lane == 0) {
        rsnu[2 * w]     = rsqrtf(na);
        rsnu[2 * w + 1] = rsqrtf(nb);
        #pragma unroll
        for (int j = 0; j < kNF; ++j) {
            sdot[2 * w][j]     = da[j];
            sdot[2 * w + 1][j] = db[j];
        }
    }
    __syncthreads();

    // ---- two DPs on lanes 0..15 of wave 0: 0-7 dp(D), 8-15 dp(D^T).
    //      Normalization fused into the matrix access (validated in V3b). ----
    if (t < 16) {
        const int  r  = t & 7;
        const bool xp = t >= 8;

        auto Dm = [&](int rr, int ii) -> float {
            return xp ? sdot[ii][rr] * rsnu[ii] * rnv[rr]
                      : sdot[rr][ii] * rsnu[rr] * rnv[ii];
        };

        float prev = Dm(r, 0);
        #pragma unroll
        for (int i = 1; i < kNF; ++i) {
            float up = __shfl_up(prev, 1, 64);  // prev[r-1]; unused when r==0
            float d  = Dm(r, i);
            float mx = fmaxf(up, prev);
            float mn = fminf(up, prev);
            float lse = mx + kLam * log1pf(expf((mn - mx) * kInvLam));
            prev = (r == 0) ? (prev + d) : (lse + d);
        }
        // lam*logsumexp over the 8 rows (xor 4,2,1 stays in 8-lane group)
        float mx = prev;
        #pragma unroll
        for (int m = 4; m >= 1; m >>= 1) mx = fmaxf(mx, __shfl_xor(mx, m, 64));
        float e = expf((prev - mx) * kInvLam);
        #pragma unroll
        for (int m = 4; m >= 1; m >>= 1) e += __shfl_xor(e, m, 64);
        float res = mx + kLam * logf(e);

        float resT = __shfl(res, r + 8, 64);    // pair dp1 lane with dp2 lane
        if (t == 0) out[(size_t)s * kBS + b] = 0.5f * (res + resT);
    }
}

extern "C" void kernel_launch(void* const* d_in, const int* in_sizes, int n_in,
                              void* d_out, int out_size, void* d_ws, size_t ws_size,
                              hipStream_t stream) {
    const float* sv = (const float*)d_in[0];
    const float* tv = (const float*)d_in[1];
    float* out = (float*)d_out;
    otam_kernel<<<dim3(kSeq * kBS), dim3(256), 0, stream>>>(sv, tv, out);
}